// Round 20
// baseline (7867.861 us; speedup 1.0000x reference)
//
#include <hip/hip_runtime.h>

#define Bdim 128
#define Tdim 256
#define Fdim 64
#define Hdim 1024
#define Pdim 512
#define OUTLEN 48

typedef float  f32x4 __attribute__((ext_vector_type(4)));
typedef short  s16x8 __attribute__((ext_vector_type(8)));
typedef unsigned short u16;

__device__ __forceinline__ u16 f2bf(float f) {
  unsigned u = __float_as_uint(f);
  u += 0x7FFFu + ((u >> 16) & 1u);   // RNE
  return (u16)(u >> 16);
}
__device__ __forceinline__ float bf2f(u16 s) { return __uint_as_float(((unsigned)s) << 16); }
// 16B-block XOR swizzle within a 128B row (G4 pattern); returns u16 offset of block
__device__ __forceinline__ int swz8(int row, int blk) { return ((blk ^ (row & 7)) << 3); }

__device__ __forceinline__ f32x4 mfma16(s16x8 a, s16x8 b, f32x4 c) {
  return __builtin_amdgcn_mfma_f32_16x16x32_bf16(a, b, c, 0, 0, 0);
}

// async global->LDS, 16B per lane; lds base must be wave-uniform (HW adds lane*16)
__device__ __forceinline__ void glds16(u16* lds, const u16* g) {
  __builtin_amdgcn_global_load_lds(
      (const __attribute__((address_space(1))) unsigned int*)g,
      (__attribute__((address_space(3))) unsigned int*)lds, 16, 0, 0);
}

// =====================================================================
// prep: fp32 weight [N][K] -> swizzled bf16 HI-ONLY tiles (16-col blocks)
// layout: [colblk][nc][rows][64]  (rows = 48 gru / 16 lin)
// =====================================================================
__global__ __launch_bounds__(256)
void prep_w(const float* __restrict__ W, u16* __restrict__ dst,
            int colblks, int nc, int rows, int K, int gru) {
  int idx = blockIdx.x * 256 + threadIdx.x;
  if (idx >= colblks * nc * rows * 8) return;
  int blk = idx & 7;
  int t = idx >> 3;
  int r = t % rows; t /= rows;
  int c = t % nc;
  int cb = t / nc;
  int srow = gru ? ((r >> 4) * Hdim + cb * 16 + (r & 15)) : (cb * 16 + r);
  const float* src = W + (size_t)srow * K + c * 64 + blk * 8;
  s16x8 vh;
#pragma unroll
  for (int e = 0; e < 8; ++e) vh[e] = (short)f2bf(src[e]);
  size_t tb = (size_t)(cb * nc + c) * (rows * 64);
  *(s16x8*)(dst + tb + r * 64 + swz8(r, blk)) = vh;
}

// X [128][256][64] fp32 -> per-t A-tiles [256][2][128][64] (hi+lo planes;
// lo plane kept for layout compatibility, not fed to MFMA)
__global__ __launch_bounds__(256)
void prep_x(const float* __restrict__ X, u16* __restrict__ dst) {
  int idx = blockIdx.x * 256 + threadIdx.x;   // 256*128*8
  int blk = idx & 7;
  int row = (idx >> 3) & 127;
  int t = idx >> 10;
  const float* src = X + (size_t)row * (Tdim * Fdim) + t * 64 + blk * 8;
  s16x8 vh, vl;
#pragma unroll
  for (int e = 0; e < 8; ++e) {
    float v = src[e];
    u16 h = f2bf(v);
    vh[e] = (short)h;
    vl[e] = (short)f2bf(v - bf2f(h));
  }
  size_t tb = (size_t)t * 16384;
  int o = row * 64 + swz8(row, blk);
  *(s16x8*)(dst + tb + o) = vh;
  *(s16x8*)(dst + tb + 8192 + o) = vl;
}

// =====================================================================
// one staged 64-k chunk, A-HI-ONLY (1-term: ah*bh). Carry state stays
// fp32-exact via hi+lo planes in the epilogue.
// LDS buf: A hi[AROWS][64] | W hi[NG*16][64]
// =====================================================================
template<int NG, bool SEG1, int AROWS>
__device__ __forceinline__ void compute_chunk(const u16* __restrict__ A, int lane, int wv,
                                              f32x4* acc) {
  const u16* Wp = A + AROWS * 64;
#pragma unroll
  for (int kk = 0; kk < 2; ++kk) {
    const int sw = (((kk * 4 + (lane >> 4)) ^ (lane & 7)) << 3);
    s16x8 bh[NG];
#pragma unroll
    for (int g = 0; g < NG; ++g)
      bh[g] = *(const s16x8*)(Wp + (g * 16 + (lane & 15)) * 64 + sw);
    const u16* ap = A + (wv * 16 + (lane & 15)) * 64 + sw;
    s16x8 ah = *(const s16x8*)(ap);
#pragma unroll
    for (int g = 0; g < NG; ++g) {
      const int q = (NG == 3 && g == 2) ? (SEG1 ? 3 : 2) : g;
      acc[q] = mfma16(ah, bh[g], acc[q]);
    }
  }
}

// =====================================================================
struct GArgs {
  const u16* a0; const u16* w0; int nc0;
  const u16* a1; const u16* w1; int nc1;
  const float* bias0; const float* bias1;
  const u16* hprev; u16* oplanes; float* yout;
};

// ---------------------------------------------------------------------
// shared epilogue (j = cb*16 + lane&15); hprev read + h write use BOTH
// planes -> recurrent carry is fp32-exact.
// ---------------------------------------------------------------------
template<int MODE, int NQ>
__device__ __forceinline__ void epilogue(const GArgs& g, const f32x4* acc,
                                         int cb, int rowbase, int lane) {
  const int j = cb * 16 + (lane & 15);
  const int ch = j >> 6, k6 = j & 63;
  if constexpr (MODE == 0) {
    const float b_r = g.bias0[j] + g.bias1[j];
    const float b_z = g.bias0[Hdim + j] + g.bias1[Hdim + j];
    const float b_in = g.bias0[2 * Hdim + j];
    const float b_hn = g.bias1[2 * Hdim + j];
#pragma unroll
    for (int e = 0; e < 4; ++e) {
      const int r = rowbase + e;
      const int o = ch * 16384 + r * 64 + swz8(r, k6 >> 3) + (k6 & 7);
      const float hp = bf2f(g.hprev[o]) + bf2f(g.hprev[o + 8192]);
      const float rr = 1.f / (1.f + expf(-(acc[0][e] + b_r)));
      const float zz = 1.f / (1.f + expf(-(acc[1][e] + b_z)));
      const float nn = tanhf(acc[2][e] + b_in + rr * (acc[3][e] + b_hn));
      const float h = (1.f - zz) * nn + zz * hp;
      const u16 hh = f2bf(h);
      g.oplanes[o] = hh;
      g.oplanes[o + 8192] = f2bf(h - bf2f(hh));
    }
  } else {
    const float bb = g.bias0[j];
#pragma unroll
    for (int e = 0; e < 4; ++e) {
      const int r = rowbase + e;
      float v = acc[0][e] + bb;
      if constexpr (MODE == 1) v = fmaxf(v, 0.f);
      const int o = ch * 16384 + r * 64 + swz8(r, k6 >> 3) + (k6 & 7);
      const u16 hh = f2bf(v);
      g.oplanes[o] = hh;
      g.oplanes[o + 8192] = f2bf(v - bf2f(hh));
      if constexpr (MODE == 2) g.yout[(size_t)r * (OUTLEN * Fdim) + j] = v;
    }
  }
}

// =====================================================================
// ENCODER body (r19 + distance-2 pipeline): 256 thr / 4 waves / 64 rows,
// SIX LDS buffers (chunk c -> buf c%6). Phase: {barrier; stage c+4,c+5;
// vmcnt(k*issue); compute c,c+1; lgkmcnt(0)}. k = clamp(NC-c-2, 0, 4).
// Per-chunk issues/wave: A 2 + W {2|1} -> hiw(wv<2)=4, low=3 (uniform
// across ALL chunks incl. the x chunk). NG=1: 3|2.
// =====================================================================
template<int NG, int MODE>
__device__ __forceinline__ void gemm_body(u16* __restrict__ sm, const GArgs& g,
                                          int cb, int rh) {
  constexpr int WT = NG * 1024;
  constexpr int BUFU = 4096 + WT;          // A hi (64 rows) + W hi
  constexpr int NQ = (NG == 3) ? 4 : 1;

  const int tid = threadIdx.x;
  const int lane = tid & 63;
  const int wv = tid >> 6;
  const bool hiw = (wv < 2);
  const int nc0 = g.nc0;
  const int NC = nc0 + g.nc1;

  f32x4 acc[NQ];
#pragma unroll
  for (int q = 0; q < NQ; ++q) acc[q] = f32x4{0.f, 0.f, 0.f, 0.f};

  auto stage = [&](int c, int buf) {
    const u16 *at, *wt;
    if (c < nc0) { at = g.a0 + (size_t)c * 16384; wt = g.w0 + (size_t)(cb * nc0 + c) * WT; }
    else { int cc = c - nc0; at = g.a1 + (size_t)cc * 16384; wt = g.w1 + (size_t)(cb * g.nc1 + cc) * WT; }
    u16* sa = sm + buf * BUFU;
    for (int i = wv; i < 8; i += 4)                  // A hi half: 2 issues/wave
      glds16(sa + i * 512, at + rh * 4096 + i * 512 + lane * 8);
    u16* swl = sa + 4096;
    for (int i = wv; i < (WT >> 9); i += 4)          // W hi: 6 (GRU) / 2 (LIN) segs
      glds16(swl + i * 512, wt + i * 512 + lane * 8);
  };

  for (int p = 0; p < 4 && p < NC; ++p) stage(p, p);  // prologue: chunks 0..3
  for (int c = 0; c < NC; c += 2) {
    __builtin_amdgcn_s_barrier();                    // bufs of c-2,c-1 free now
    asm volatile("" ::: "memory");
    if (c + 4 < NC) stage(c + 4, (c + 4) % 6);
    if (c + 5 < NC) stage(c + 5, (c + 5) % 6);
    int k = NC - c - 2; if (k > 4) k = 4; if (k < 0) k = 0;
    if constexpr (NG == 3) {
      switch (hiw ? k * 4 : k * 3) {
        case 16: asm volatile("s_waitcnt vmcnt(16)" ::: "memory"); break;
        case 12: asm volatile("s_waitcnt vmcnt(12)" ::: "memory"); break;
        case 9:  asm volatile("s_waitcnt vmcnt(9)"  ::: "memory"); break;
        case 8:  asm volatile("s_waitcnt vmcnt(8)"  ::: "memory"); break;
        case 6:  asm volatile("s_waitcnt vmcnt(6)"  ::: "memory"); break;
        case 4:  asm volatile("s_waitcnt vmcnt(4)"  ::: "memory"); break;
        case 3:  asm volatile("s_waitcnt vmcnt(3)"  ::: "memory"); break;
        default: asm volatile("s_waitcnt vmcnt(0)"  ::: "memory");
      }
    } else {
      switch (hiw ? k * 3 : k * 2) {
        case 12: asm volatile("s_waitcnt vmcnt(12)" ::: "memory"); break;
        case 9:  asm volatile("s_waitcnt vmcnt(9)"  ::: "memory"); break;
        case 8:  asm volatile("s_waitcnt vmcnt(8)"  ::: "memory"); break;
        case 6:  asm volatile("s_waitcnt vmcnt(6)"  ::: "memory"); break;
        case 4:  asm volatile("s_waitcnt vmcnt(4)"  ::: "memory"); break;
        case 3:  asm volatile("s_waitcnt vmcnt(3)"  ::: "memory"); break;
        case 2:  asm volatile("s_waitcnt vmcnt(2)"  ::: "memory"); break;
        default: asm volatile("s_waitcnt vmcnt(0)"  ::: "memory");
      }
    }
    asm volatile("" ::: "memory");
    const u16* A0 = sm + (c % 6) * BUFU;
    if (c < nc0) compute_chunk<NG, false, 64>(A0, lane, wv, acc);
    else         compute_chunk<NG, true, 64>(A0, lane, wv, acc);
    if (c + 1 < NC) {
      const u16* A1 = sm + ((c + 1) % 6) * BUFU;
      if (c + 1 < nc0) compute_chunk<NG, false, 64>(A1, lane, wv, acc);
      else             compute_chunk<NG, true, 64>(A1, lane, wv, acc);
    }
    asm volatile("s_waitcnt lgkmcnt(0)" ::: "memory");
  }

  const int rowbase = rh * 64 + wv * 16 + ((lane >> 4) << 2);
  epilogue<MODE, NQ>(g, acc, cb, rowbase, lane);
}

// =====================================================================
// DECODER body (r19 + distance-2): 128 thr / 2 waves / 32 rows x 16 cols,
// six buffers. Per-chunk issues/wave uniform: GRU 5, LIN 3.
// vmcnt = k*5 (GRU) / k*3 (LIN), k = clamp(NC-c-2, 0, 4).
// =====================================================================
template<int NG, int MODE>
__device__ __forceinline__ void gemm_body32(u16* __restrict__ sm, const GArgs& g,
                                            int cb, int rq) {
  constexpr int WT = NG * 1024;
  constexpr int BUFU = 2048 + WT;          // A hi (32 rows) + W hi
  constexpr int NQ = (NG == 3) ? 4 : 1;

  const int tid = threadIdx.x;
  const int lane = tid & 63;
  const int wv = tid >> 6;                 // 0..1
  const int nc0 = g.nc0;
  const int NC = nc0 + g.nc1;

  f32x4 acc[NQ];
#pragma unroll
  for (int q = 0; q < NQ; ++q) acc[q] = f32x4{0.f, 0.f, 0.f, 0.f};

  auto stage = [&](int c, int buf) {
    const u16 *at, *wt;
    if (c < nc0) { at = g.a0 + (size_t)c * 16384; wt = g.w0 + (size_t)(cb * nc0 + c) * WT; }
    else { int cc = c - nc0; at = g.a1 + (size_t)cc * 16384; wt = g.w1 + (size_t)(cb * g.nc1 + cc) * WT; }
    u16* sa = sm + buf * BUFU;
    for (int i = wv; i < 4; i += 2)        // A hi quarter: 2 issues/wave
      glds16(sa + i * 512, at + rq * 2048 + i * 512 + lane * 8);
    u16* swl = sa + 2048;
    for (int i = wv; i < (WT >> 9); i += 2) // W hi: 3 (GRU) / 1 (LIN) per wave
      glds16(swl + i * 512, wt + i * 512 + lane * 8);
  };

  for (int p = 0; p < 4 && p < NC; ++p) stage(p, p);  // prologue: chunks 0..3
  for (int c = 0; c < NC; c += 2) {
    __builtin_amdgcn_s_barrier();
    asm volatile("" ::: "memory");
    if (c + 4 < NC) stage(c + 4, (c + 4) % 6);
    if (c + 5 < NC) stage(c + 5, (c + 5) % 6);
    int k = NC - c - 2; if (k > 4) k = 4; if (k < 0) k = 0;
    if constexpr (NG == 3) {
      switch (k) {
        case 4:  asm volatile("s_waitcnt vmcnt(20)" ::: "memory"); break;
        case 3:  asm volatile("s_waitcnt vmcnt(15)" ::: "memory"); break;
        case 2:  asm volatile("s_waitcnt vmcnt(10)" ::: "memory"); break;
        case 1:  asm volatile("s_waitcnt vmcnt(5)"  ::: "memory"); break;
        default: asm volatile("s_waitcnt vmcnt(0)"  ::: "memory");
      }
    } else {
      switch (k) {
        case 4:  asm volatile("s_waitcnt vmcnt(12)" ::: "memory"); break;
        case 3:  asm volatile("s_waitcnt vmcnt(9)"  ::: "memory"); break;
        case 2:  asm volatile("s_waitcnt vmcnt(6)"  ::: "memory"); break;
        case 1:  asm volatile("s_waitcnt vmcnt(3)"  ::: "memory"); break;
        default: asm volatile("s_waitcnt vmcnt(0)"  ::: "memory");
      }
    }
    asm volatile("" ::: "memory");
    const u16* A0 = sm + (c % 6) * BUFU;
    if (c < nc0) compute_chunk<NG, false, 32>(A0, lane, wv, acc);
    else         compute_chunk<NG, true, 32>(A0, lane, wv, acc);
    if (c + 1 < NC) {
      const u16* A1 = sm + ((c + 1) % 6) * BUFU;
      if (c + 1 < nc0) compute_chunk<NG, false, 32>(A1, lane, wv, acc);
      else             compute_chunk<NG, true, 32>(A1, lane, wv, acc);
    }
    asm volatile("s_waitcnt lgkmcnt(0)" ::: "memory");
  }

  const int rowbase = rq * 32 + wv * 16 + ((lane >> 4) << 2);
  epilogue<MODE, NQ>(g, acc, cb, rowbase, lane);
}

template<int NG, int MODE>
__global__ __launch_bounds__(256)
void fused_gemm(GArgs g) {
  __shared__ u16 sm[6 * (4096 + NG * 1024)];
  gemm_body<NG, MODE>(sm, g, blockIdx.x, blockIdx.y);
}

// encoder pair: x<64 -> layer-0 step t, x>=64 -> layer-1 step t-1; y = row-half
__global__ __launch_bounds__(256)
void gru_pair(GArgs ga, GArgs gb) {
  __shared__ u16 sm[6 * (4096 + 3 * 1024)];
  if (blockIdx.x < 64) gemm_body<3, 0>(sm, ga, blockIdx.x, blockIdx.y);
  else                 gemm_body<3, 0>(sm, gb, blockIdx.x - 64, blockIdx.y);
}

template<int NG, int MODE>
__global__ __launch_bounds__(128)
void fused_gemm32(GArgs g) {
  __shared__ u16 sm[6 * (2048 + NG * 1024)];
  gemm_body32<NG, MODE>(sm, g, blockIdx.x, blockIdx.y);
}

// =====================================================================
extern "C" void kernel_launch(void* const* d_in, const int* in_sizes, int n_in,
                              void* d_out, int out_size, void* d_ws, size_t ws_size,
                              hipStream_t stream) {
  const float* X     = (const float*)d_in[0];
  const float* eWih0 = (const float*)d_in[1];
  const float* eWhh0 = (const float*)d_in[2];
  const float* ebih0 = (const float*)d_in[3];
  const float* ebhh0 = (const float*)d_in[4];
  const float* eWih1 = (const float*)d_in[5];
  const float* eWhh1 = (const float*)d_in[6];
  const float* ebih1 = (const float*)d_in[7];
  const float* ebhh1 = (const float*)d_in[8];
  const float* dWih0 = (const float*)d_in[9];
  const float* dWhh0 = (const float*)d_in[10];
  const float* dbih0 = (const float*)d_in[11];
  const float* dbhh0 = (const float*)d_in[12];
  const float* dWih1 = (const float*)d_in[13];
  const float* dWhh1 = (const float*)d_in[14];
  const float* dbih1 = (const float*)d_in[15];
  const float* dbhh1 = (const float*)d_in[16];
  const float* projW = (const float*)d_in[17];
  const float* projb = (const float*)d_in[18];
  const float* outW  = (const float*)d_in[19];
  const float* outb  = (const float*)d_in[20];
  float* outf = (float*)d_out;

  u16* wsp = (u16*)d_ws;
  size_t off = 0;
  auto take = [&](size_t n) { u16* p = wsp + off; off += n; return p; };

  u16* pl_eWih0 = take(64ULL * 1 * 48 * 64);        // hi-only 16-col W tiles
  u16* pl_eWhh0 = take(64ULL * 16 * 48 * 64);
  u16* pl_eWih1 = take(64ULL * 16 * 48 * 64);
  u16* pl_eWhh1 = take(64ULL * 16 * 48 * 64);
  u16* pl_dWih0 = take(64ULL * 1 * 48 * 64);
  u16* pl_dWhh0 = take(64ULL * 16 * 48 * 64);
  u16* pl_dWih1 = take(64ULL * 16 * 48 * 64);
  u16* pl_dWhh1 = take(64ULL * 16 * 48 * 64);
  u16* pl_proj  = take(32ULL * 16 * 16 * 64);
  u16* pl_out   = take(4ULL * 8 * 16 * 64);
  u16* pl_x     = take(256ULL * 2 * 128 * 64);
  u16* pl_h0    = take(2ULL * 16 * 2 * 128 * 64);   // 2 slots, stride 262144
  u16* pl_h1    = take(2ULL * 16 * 2 * 128 * 64);
  u16* pl_y     = take(2ULL * 1 * 2 * 128 * 64);    // 2 slots, stride 16384
  u16* pl_p     = take(8ULL * 2 * 128 * 64);
  if (off * 2 > ws_size) return;                    // scratch too small -> loud fail

  hipMemsetAsync(pl_h0, 0, 262144 * 2, stream);     // h0 slot0 = 0
  hipMemsetAsync(pl_h1, 0, 262144 * 2, stream);     // h1 slot0 = 0

  auto pw = [&](const float* W, u16* dst, int colblks, int nc, int rows, int K, int gru) {
    int total = colblks * nc * rows * 8;
    prep_w<<<(total + 255) / 256, 256, 0, stream>>>(W, dst, colblks, nc, rows, K, gru);
  };
  pw(eWih0, pl_eWih0, 64, 1, 48, 64, 1);
  pw(eWhh0, pl_eWhh0, 64, 16, 48, 1024, 1);
  pw(eWih1, pl_eWih1, 64, 16, 48, 1024, 1);
  pw(eWhh1, pl_eWhh1, 64, 16, 48, 1024, 1);
  pw(dWih0, pl_dWih0, 64, 1, 48, 64, 1);
  pw(dWhh0, pl_dWhh0, 64, 16, 48, 1024, 1);
  pw(dWih1, pl_dWih1, 64, 16, 48, 1024, 1);
  pw(dWhh1, pl_dWhh1, 64, 16, 48, 1024, 1);
  pw(projW, pl_proj, 32, 16, 16, 1024, 0);
  pw(outW,  pl_out,  4,  8,  16, 512, 0);
  prep_x<<<1024, 256, 0, stream>>>(X, pl_x);

  // nc0 MUST be threaded through: 1 for x-input (K=64), 16 for h-input (K=1024).
  auto mkL0 = [&](int t, const u16* xs) {
    const u16* h0i = pl_h0 + (size_t)(t & 1) * 262144;
    u16* h0o = pl_h0 + (size_t)((t + 1) & 1) * 262144;
    return GArgs{xs, pl_eWih0, 1, h0i, pl_eWhh0, 16, ebih0, ebhh0, h0i, h0o, nullptr};
  };
  // encoder layer-1, step u: activation = h0 slot((u+1)&1), state = h1 slot(u&1)
  auto mkL1e = [&](int u) {
    const u16* act = pl_h0 + (size_t)((u + 1) & 1) * 262144;
    const u16* h1i = pl_h1 + (size_t)(u & 1) * 262144;
    u16* h1o = pl_h1 + (size_t)((u + 1) & 1) * 262144;
    return GArgs{act, pl_eWih1, 16, h1i, pl_eWhh1, 16, ebih1, ebhh1, h1i, h1o, nullptr};
  };

  // ---------------- encoder: L0[t] || L1[t-1] fused ----------------
  {
    GArgs g0 = mkL0(0, pl_x);
    fused_gemm<3, 0><<<dim3(64, 2), 256, 0, stream>>>(g0);
  }
  for (int t = 1; t < Tdim; ++t) {
    GArgs gA = mkL0(t, pl_x + (size_t)t * 16384);
    GArgs gB = mkL1e(t - 1);
    gru_pair<<<dim3(128, 2), 256, 0, stream>>>(gA, gB);
  }
  {
    GArgs gB = mkL1e(Tdim - 1);
    fused_gemm<3, 0><<<dim3(64, 2), 256, 0, stream>>>(gB);
  }

  // ---------------- decoder ----------------
  for (int s = 0; s < OUTLEN; ++s) {
    const u16* xs = (s == 0) ? (pl_x + 255ULL * 16384) : (pl_y + (size_t)((s - 1) & 1) * 16384);
    const u16* h0i = pl_h0 + (size_t)(s & 1) * 262144;
    u16* h0o = pl_h0 + (size_t)((s + 1) & 1) * 262144;
    const u16* h1i = pl_h1 + (size_t)(s & 1) * 262144;
    u16* h1o = pl_h1 + (size_t)((s + 1) & 1) * 262144;

    GArgs g0{xs, pl_dWih0, 1, h0i, pl_dWhh0, 16, dbih0, dbhh0, h0i, h0o, nullptr};
    fused_gemm32<3, 0><<<dim3(64, 4), 128, 0, stream>>>(g0);
    GArgs g1{h0o, pl_dWih1, 16, h1i, pl_dWhh1, 16, dbih1, dbhh1, h1i, h1o, nullptr};
    fused_gemm32<3, 0><<<dim3(64, 4), 128, 0, stream>>>(g1);
    GArgs gp{h1o, pl_proj, 16, nullptr, nullptr, 0, projb, nullptr, nullptr, pl_p, nullptr};
    fused_gemm32<1, 1><<<dim3(32, 4), 128, 0, stream>>>(gp);
    GArgs gy{pl_p, pl_out, 8, nullptr, nullptr, 0, outb, nullptr, nullptr,
             pl_y + (size_t)(s & 1) * 16384, outf + (size_t)s * 64};
    fused_gemm32<1, 2><<<dim3(4, 4), 128, 0, stream>>>(gy);
  }
}

// Round 21
// 7343.981 us; speedup vs baseline: 1.0713x; 1.0713x over previous
//
#include <hip/hip_runtime.h>

#define Bdim 128
#define Tdim 256
#define Fdim 64
#define Hdim 1024
#define Pdim 512
#define OUTLEN 48

typedef float  f32x4 __attribute__((ext_vector_type(4)));
typedef short  s16x8 __attribute__((ext_vector_type(8)));
typedef unsigned short u16;

__device__ __forceinline__ u16 f2bf(float f) {
  unsigned u = __float_as_uint(f);
  u += 0x7FFFu + ((u >> 16) & 1u);   // RNE
  return (u16)(u >> 16);
}
__device__ __forceinline__ float bf2f(u16 s) { return __uint_as_float(((unsigned)s) << 16); }
// 16B-block XOR swizzle within a 128B row (G4 pattern); returns u16 offset of block
__device__ __forceinline__ int swz8(int row, int blk) { return ((blk ^ (row & 7)) << 3); }

__device__ __forceinline__ f32x4 mfma16(s16x8 a, s16x8 b, f32x4 c) {
  return __builtin_amdgcn_mfma_f32_16x16x32_bf16(a, b, c, 0, 0, 0);
}

// async global->LDS, 16B per lane; lds base must be wave-uniform (HW adds lane*16)
__device__ __forceinline__ void glds16(u16* lds, const u16* g) {
  __builtin_amdgcn_global_load_lds(
      (const __attribute__((address_space(1))) unsigned int*)g,
      (__attribute__((address_space(3))) unsigned int*)lds, 16, 0, 0);
}

// =====================================================================
// prep: fp32 weight [N][K] -> swizzled bf16 HI-ONLY tiles (16-col blocks)
// layout: [colblk][nc][rows][64]  (rows = 48 gru / 16 lin)
// =====================================================================
__global__ __launch_bounds__(256)
void prep_w(const float* __restrict__ W, u16* __restrict__ dst,
            int colblks, int nc, int rows, int K, int gru) {
  int idx = blockIdx.x * 256 + threadIdx.x;
  if (idx >= colblks * nc * rows * 8) return;
  int blk = idx & 7;
  int t = idx >> 3;
  int r = t % rows; t /= rows;
  int c = t % nc;
  int cb = t / nc;
  int srow = gru ? ((r >> 4) * Hdim + cb * 16 + (r & 15)) : (cb * 16 + r);
  const float* src = W + (size_t)srow * K + c * 64 + blk * 8;
  s16x8 vh;
#pragma unroll
  for (int e = 0; e < 8; ++e) vh[e] = (short)f2bf(src[e]);
  size_t tb = (size_t)(cb * nc + c) * (rows * 64);
  *(s16x8*)(dst + tb + r * 64 + swz8(r, blk)) = vh;
}

// X [128][256][64] fp32 -> per-t A-tiles [256][2][128][64] (hi+lo planes;
// lo plane is kept for layout compatibility but no longer fed to MFMA)
__global__ __launch_bounds__(256)
void prep_x(const float* __restrict__ X, u16* __restrict__ dst) {
  int idx = blockIdx.x * 256 + threadIdx.x;   // 256*128*8
  int blk = idx & 7;
  int row = (idx >> 3) & 127;
  int t = idx >> 10;
  const float* src = X + (size_t)row * (Tdim * Fdim) + t * 64 + blk * 8;
  s16x8 vh, vl;
#pragma unroll
  for (int e = 0; e < 8; ++e) {
    float v = src[e];
    u16 h = f2bf(v);
    vh[e] = (short)h;
    vl[e] = (short)f2bf(v - bf2f(h));
  }
  size_t tb = (size_t)t * 16384;
  int o = row * 64 + swz8(row, blk);
  *(s16x8*)(dst + tb + o) = vh;
  *(s16x8*)(dst + tb + 8192 + o) = vl;
}

// =====================================================================
// one staged 64-k chunk, A-HI-ONLY (1-term: ah*bh). Carry state stays
// fp32-exact via hi+lo planes in the epilogue; only the GEMM input is
// bf16-quantized. LDS buf: A hi[AROWS][64] | W hi[NG*16][64]
// =====================================================================
template<int NG, bool SEG1, int AROWS>
__device__ __forceinline__ void compute_chunk(const u16* __restrict__ A, int lane, int wv,
                                              f32x4* acc) {
  const u16* Wp = A + AROWS * 64;
#pragma unroll
  for (int kk = 0; kk < 2; ++kk) {
    const int sw = (((kk * 4 + (lane >> 4)) ^ (lane & 7)) << 3);
    s16x8 bh[NG];
#pragma unroll
    for (int g = 0; g < NG; ++g)
      bh[g] = *(const s16x8*)(Wp + (g * 16 + (lane & 15)) * 64 + sw);
    const u16* ap = A + (wv * 16 + (lane & 15)) * 64 + sw;
    s16x8 ah = *(const s16x8*)(ap);
#pragma unroll
    for (int g = 0; g < NG; ++g) {
      const int q = (NG == 3 && g == 2) ? (SEG1 ? 3 : 2) : g;
      acc[q] = mfma16(ah, bh[g], acc[q]);
    }
  }
}

// =====================================================================
struct GArgs {
  const u16* a0; const u16* w0; int nc0;
  const u16* a1; const u16* w1; int nc1;
  const float* bias0; const float* bias1;
  const u16* hprev; u16* oplanes; float* yout;
};

// ---------------------------------------------------------------------
// shared epilogue (j = cb*16 + lane&15); hprev read + h write use BOTH
// planes -> recurrent carry is fp32-exact.
// ---------------------------------------------------------------------
template<int MODE, int NQ>
__device__ __forceinline__ void epilogue(const GArgs& g, const f32x4* acc,
                                         int cb, int rowbase, int lane) {
  const int j = cb * 16 + (lane & 15);
  const int ch = j >> 6, k6 = j & 63;
  if constexpr (MODE == 0) {
    const float b_r = g.bias0[j] + g.bias1[j];
    const float b_z = g.bias0[Hdim + j] + g.bias1[Hdim + j];
    const float b_in = g.bias0[2 * Hdim + j];
    const float b_hn = g.bias1[2 * Hdim + j];
#pragma unroll
    for (int e = 0; e < 4; ++e) {
      const int r = rowbase + e;
      const int o = ch * 16384 + r * 64 + swz8(r, k6 >> 3) + (k6 & 7);
      const float hp = bf2f(g.hprev[o]) + bf2f(g.hprev[o + 8192]);
      const float rr = 1.f / (1.f + expf(-(acc[0][e] + b_r)));
      const float zz = 1.f / (1.f + expf(-(acc[1][e] + b_z)));
      const float nn = tanhf(acc[2][e] + b_in + rr * (acc[3][e] + b_hn));
      const float h = (1.f - zz) * nn + zz * hp;
      const u16 hh = f2bf(h);
      g.oplanes[o] = hh;
      g.oplanes[o + 8192] = f2bf(h - bf2f(hh));
    }
  } else {
    const float bb = g.bias0[j];
#pragma unroll
    for (int e = 0; e < 4; ++e) {
      const int r = rowbase + e;
      float v = acc[0][e] + bb;
      if constexpr (MODE == 1) v = fmaxf(v, 0.f);
      const int o = ch * 16384 + r * 64 + swz8(r, k6 >> 3) + (k6 & 7);
      const u16 hh = f2bf(v);
      g.oplanes[o] = hh;
      g.oplanes[o + 8192] = f2bf(v - bf2f(hh));
      if constexpr (MODE == 2) g.yout[(size_t)r * (OUTLEN * Fdim) + j] = v;
    }
  }
}

// =====================================================================
// ENCODER body (r19 exact): 256 thr / 4 waves / 64 rows (rh in {0,1}),
// 4 LDS buffers, distance-1 paired phases, A-hi-only.
// Per-wave issues/chunk: A 2 + W {2|1} -> hiw(wv<2)=4, low=3.
// vmcnt: nn=2 -> 8|6 ; nn=1 -> 4|3 ; else 0.  (NG=1: 3|2 -> 6|4, 3|2.)
// =====================================================================
template<int NG, int MODE>
__device__ __forceinline__ void gemm_body(u16* __restrict__ sm, const GArgs& g,
                                          int cb, int rh) {
  constexpr int WT = NG * 1024;
  constexpr int BUFU = 4096 + WT;          // A hi (64 rows) + W hi
  constexpr int NQ = (NG == 3) ? 4 : 1;

  const int tid = threadIdx.x;
  const int lane = tid & 63;
  const int wv = tid >> 6;
  const bool hiw = (wv < 2);
  const int nc0 = g.nc0;
  const int NC = nc0 + g.nc1;

  f32x4 acc[NQ];
#pragma unroll
  for (int q = 0; q < NQ; ++q) acc[q] = f32x4{0.f, 0.f, 0.f, 0.f};

  auto stage = [&](int c, int buf) {
    const u16 *at, *wt;
    if (c < nc0) { at = g.a0 + (size_t)c * 16384; wt = g.w0 + (size_t)(cb * nc0 + c) * WT; }
    else { int cc = c - nc0; at = g.a1 + (size_t)cc * 16384; wt = g.w1 + (size_t)(cb * g.nc1 + cc) * WT; }
    u16* sa = sm + buf * BUFU;
    for (int i = wv; i < 8; i += 4)                  // A hi half: 2 issues/wave
      glds16(sa + i * 512, at + rh * 4096 + i * 512 + lane * 8);
    u16* swl = sa + 4096;
    for (int i = wv; i < (WT >> 9); i += 4)          // W hi: 6 (GRU) / 2 (LIN) segs
      glds16(swl + i * 512, wt + i * 512 + lane * 8);
  };

  stage(0, 0);
  if (NC > 1) stage(1, 1);
  for (int c = 0; c < NC; c += 2) {
    __builtin_amdgcn_s_barrier();
    asm volatile("" ::: "memory");
    int nn = 0;
    if (c + 2 < NC) { stage(c + 2, (c + 2) & 3); ++nn; }
    if (c + 3 < NC) { stage(c + 3, (c + 3) & 3); ++nn; }
    if constexpr (NG == 3) {
      if (nn == 2)      { if (hiw) asm volatile("s_waitcnt vmcnt(8)" ::: "memory");
                          else     asm volatile("s_waitcnt vmcnt(6)" ::: "memory"); }
      else if (nn == 1) { if (hiw) asm volatile("s_waitcnt vmcnt(4)" ::: "memory");
                          else     asm volatile("s_waitcnt vmcnt(3)" ::: "memory"); }
      else              asm volatile("s_waitcnt vmcnt(0)" ::: "memory");
    } else {
      if (nn == 2)      { if (hiw) asm volatile("s_waitcnt vmcnt(6)" ::: "memory");
                          else     asm volatile("s_waitcnt vmcnt(4)" ::: "memory"); }
      else if (nn == 1) { if (hiw) asm volatile("s_waitcnt vmcnt(3)" ::: "memory");
                          else     asm volatile("s_waitcnt vmcnt(2)" ::: "memory"); }
      else              asm volatile("s_waitcnt vmcnt(0)" ::: "memory");
    }
    asm volatile("" ::: "memory");
    const u16* A0 = sm + (c & 3) * BUFU;
    if (c < nc0) compute_chunk<NG, false, 64>(A0, lane, wv, acc);
    else         compute_chunk<NG, true, 64>(A0, lane, wv, acc);
    if (c + 1 < NC) {
      const u16* A1 = sm + ((c + 1) & 3) * BUFU;
      if (c + 1 < nc0) compute_chunk<NG, false, 64>(A1, lane, wv, acc);
      else             compute_chunk<NG, true, 64>(A1, lane, wv, acc);
    }
    asm volatile("s_waitcnt lgkmcnt(0)" ::: "memory");
  }

  const int rowbase = rh * 64 + wv * 16 + ((lane >> 4) << 2);
  epilogue<MODE, NQ>(g, acc, cb, rowbase, lane);
}

// =====================================================================
// DECODER body (r19 exact): 128 thr / 2 waves / 32 rows (rq 0..3) x 16
// cols. Per-wave issues/chunk uniform: GRU A2+W3=5, LIN A2+W1=3.
// vmcnt: 10/5/0 (GRU), 6/3/0 (LIN).
// =====================================================================
template<int NG, int MODE>
__device__ __forceinline__ void gemm_body32(u16* __restrict__ sm, const GArgs& g,
                                            int cb, int rq) {
  constexpr int WT = NG * 1024;
  constexpr int BUFU = 2048 + WT;          // A hi (32 rows) + W hi
  constexpr int NQ = (NG == 3) ? 4 : 1;

  const int tid = threadIdx.x;
  const int lane = tid & 63;
  const int wv = tid >> 6;                 // 0..1
  const int nc0 = g.nc0;
  const int NC = nc0 + g.nc1;

  f32x4 acc[NQ];
#pragma unroll
  for (int q = 0; q < NQ; ++q) acc[q] = f32x4{0.f, 0.f, 0.f, 0.f};

  auto stage = [&](int c, int buf) {
    const u16 *at, *wt;
    if (c < nc0) { at = g.a0 + (size_t)c * 16384; wt = g.w0 + (size_t)(cb * nc0 + c) * WT; }
    else { int cc = c - nc0; at = g.a1 + (size_t)cc * 16384; wt = g.w1 + (size_t)(cb * g.nc1 + cc) * WT; }
    u16* sa = sm + buf * BUFU;
    for (int i = wv; i < 4; i += 2)        // A hi quarter: 2 issues/wave
      glds16(sa + i * 512, at + rq * 2048 + i * 512 + lane * 8);
    u16* swl = sa + 2048;
    for (int i = wv; i < (WT >> 9); i += 2) // W hi: 3 (GRU) / 1 (LIN) per wave
      glds16(swl + i * 512, wt + i * 512 + lane * 8);
  };

  stage(0, 0);
  if (NC > 1) stage(1, 1);
  for (int c = 0; c < NC; c += 2) {
    __builtin_amdgcn_s_barrier();
    asm volatile("" ::: "memory");
    int nn = 0;
    if (c + 2 < NC) { stage(c + 2, (c + 2) & 3); ++nn; }
    if (c + 3 < NC) { stage(c + 3, (c + 3) & 3); ++nn; }
    if constexpr (NG == 3) {
      if (nn == 2)      asm volatile("s_waitcnt vmcnt(10)" ::: "memory");
      else if (nn == 1) asm volatile("s_waitcnt vmcnt(5)"  ::: "memory");
      else              asm volatile("s_waitcnt vmcnt(0)"  ::: "memory");
    } else {
      if (nn == 2)      asm volatile("s_waitcnt vmcnt(6)" ::: "memory");
      else if (nn == 1) asm volatile("s_waitcnt vmcnt(3)" ::: "memory");
      else              asm volatile("s_waitcnt vmcnt(0)" ::: "memory");
    }
    asm volatile("" ::: "memory");
    const u16* A0 = sm + (c & 3) * BUFU;
    if (c < nc0) compute_chunk<NG, false, 32>(A0, lane, wv, acc);
    else         compute_chunk<NG, true, 32>(A0, lane, wv, acc);
    if (c + 1 < NC) {
      const u16* A1 = sm + ((c + 1) & 3) * BUFU;
      if (c + 1 < nc0) compute_chunk<NG, false, 32>(A1, lane, wv, acc);
      else             compute_chunk<NG, true, 32>(A1, lane, wv, acc);
    }
    asm volatile("s_waitcnt lgkmcnt(0)" ::: "memory");
  }

  const int rowbase = rq * 32 + wv * 16 + ((lane >> 4) << 2);
  epilogue<MODE, NQ>(g, acc, cb, rowbase, lane);
}

template<int NG, int MODE>
__global__ __launch_bounds__(256)
void fused_gemm(GArgs g) {
  __shared__ u16 sm[4 * (4096 + NG * 1024)];
  gemm_body<NG, MODE>(sm, g, blockIdx.x, blockIdx.y);
}

// encoder pair: x<64 -> layer-0 step t, x>=64 -> layer-1 step t-1; y = row-half
__global__ __launch_bounds__(256)
void gru_pair(GArgs ga, GArgs gb) {
  __shared__ u16 sm[4 * (4096 + 3 * 1024)];
  if (blockIdx.x < 64) gemm_body<3, 0>(sm, ga, blockIdx.x, blockIdx.y);
  else                 gemm_body<3, 0>(sm, gb, blockIdx.x - 64, blockIdx.y);
}

template<int NG, int MODE>
__global__ __launch_bounds__(128)
void fused_gemm32(GArgs g) {
  __shared__ u16 sm[4 * (2048 + NG * 1024)];
  gemm_body32<NG, MODE>(sm, g, blockIdx.x, blockIdx.y);
}

// =====================================================================
extern "C" void kernel_launch(void* const* d_in, const int* in_sizes, int n_in,
                              void* d_out, int out_size, void* d_ws, size_t ws_size,
                              hipStream_t stream) {
  const float* X     = (const float*)d_in[0];
  const float* eWih0 = (const float*)d_in[1];
  const float* eWhh0 = (const float*)d_in[2];
  const float* ebih0 = (const float*)d_in[3];
  const float* ebhh0 = (const float*)d_in[4];
  const float* eWih1 = (const float*)d_in[5];
  const float* eWhh1 = (const float*)d_in[6];
  const float* ebih1 = (const float*)d_in[7];
  const float* ebhh1 = (const float*)d_in[8];
  const float* dWih0 = (const float*)d_in[9];
  const float* dWhh0 = (const float*)d_in[10];
  const float* dbih0 = (const float*)d_in[11];
  const float* dbhh0 = (const float*)d_in[12];
  const float* dWih1 = (const float*)d_in[13];
  const float* dWhh1 = (const float*)d_in[14];
  const float* dbih1 = (const float*)d_in[15];
  const float* dbhh1 = (const float*)d_in[16];
  const float* projW = (const float*)d_in[17];
  const float* projb = (const float*)d_in[18];
  const float* outW  = (const float*)d_in[19];
  const float* outb  = (const float*)d_in[20];
  float* outf = (float*)d_out;

  u16* wsp = (u16*)d_ws;
  size_t off = 0;
  auto take = [&](size_t n) { u16* p = wsp + off; off += n; return p; };

  u16* pl_eWih0 = take(64ULL * 1 * 48 * 64);        // hi-only 16-col W tiles
  u16* pl_eWhh0 = take(64ULL * 16 * 48 * 64);
  u16* pl_eWih1 = take(64ULL * 16 * 48 * 64);
  u16* pl_eWhh1 = take(64ULL * 16 * 48 * 64);
  u16* pl_dWih0 = take(64ULL * 1 * 48 * 64);
  u16* pl_dWhh0 = take(64ULL * 16 * 48 * 64);
  u16* pl_dWih1 = take(64ULL * 16 * 48 * 64);
  u16* pl_dWhh1 = take(64ULL * 16 * 48 * 64);
  u16* pl_proj  = take(32ULL * 16 * 16 * 64);
  u16* pl_out   = take(4ULL * 8 * 16 * 64);
  u16* pl_x     = take(256ULL * 2 * 128 * 64);
  u16* pl_h0    = take(2ULL * 16 * 2 * 128 * 64);   // 2 slots, stride 262144
  u16* pl_h1    = take(2ULL * 16 * 2 * 128 * 64);
  u16* pl_y     = take(2ULL * 1 * 2 * 128 * 64);    // 2 slots, stride 16384
  u16* pl_p     = take(8ULL * 2 * 128 * 64);
  if (off * 2 > ws_size) return;                    // scratch too small -> loud fail

  hipMemsetAsync(pl_h0, 0, 262144 * 2, stream);     // h0 slot0 = 0
  hipMemsetAsync(pl_h1, 0, 262144 * 2, stream);     // h1 slot0 = 0

  auto pw = [&](const float* W, u16* dst, int colblks, int nc, int rows, int K, int gru) {
    int total = colblks * nc * rows * 8;
    prep_w<<<(total + 255) / 256, 256, 0, stream>>>(W, dst, colblks, nc, rows, K, gru);
  };
  pw(eWih0, pl_eWih0, 64, 1, 48, 64, 1);
  pw(eWhh0, pl_eWhh0, 64, 16, 48, 1024, 1);
  pw(eWih1, pl_eWih1, 64, 16, 48, 1024, 1);
  pw(eWhh1, pl_eWhh1, 64, 16, 48, 1024, 1);
  pw(dWih0, pl_dWih0, 64, 1, 48, 64, 1);
  pw(dWhh0, pl_dWhh0, 64, 16, 48, 1024, 1);
  pw(dWih1, pl_dWih1, 64, 16, 48, 1024, 1);
  pw(dWhh1, pl_dWhh1, 64, 16, 48, 1024, 1);
  pw(projW, pl_proj, 32, 16, 16, 1024, 0);
  pw(outW,  pl_out,  4,  8,  16, 512, 0);
  prep_x<<<1024, 256, 0, stream>>>(X, pl_x);

  // nc0 MUST be threaded through: 1 for x-input (K=64), 16 for h-input (K=1024).
  auto mkL0 = [&](int t, const u16* xs) {
    const u16* h0i = pl_h0 + (size_t)(t & 1) * 262144;
    u16* h0o = pl_h0 + (size_t)((t + 1) & 1) * 262144;
    return GArgs{xs, pl_eWih0, 1, h0i, pl_eWhh0, 16, ebih0, ebhh0, h0i, h0o, nullptr};
  };
  // encoder layer-1, step u: activation = h0 slot((u+1)&1), state = h1 slot(u&1)
  auto mkL1e = [&](int u) {
    const u16* act = pl_h0 + (size_t)((u + 1) & 1) * 262144;
    const u16* h1i = pl_h1 + (size_t)(u & 1) * 262144;
    u16* h1o = pl_h1 + (size_t)((u + 1) & 1) * 262144;
    return GArgs{act, pl_eWih1, 16, h1i, pl_eWhh1, 16, ebih1, ebhh1, h1i, h1o, nullptr};
  };

  // ---------------- encoder: L0[t] || L1[t-1] fused (r19 structure) ----------------
  {
    GArgs g0 = mkL0(0, pl_x);
    fused_gemm<3, 0><<<dim3(64, 2), 256, 0, stream>>>(g0);
  }
  for (int t = 1; t < Tdim; ++t) {
    GArgs gA = mkL0(t, pl_x + (size_t)t * 16384);
    GArgs gB = mkL1e(t - 1);
    gru_pair<<<dim3(128, 2), 256, 0, stream>>>(gA, gB);
  }
  {
    GArgs gB = mkL1e(Tdim - 1);
    fused_gemm<3, 0><<<dim3(64, 2), 256, 0, stream>>>(gB);
  }

  // ---------------- decoder: r19-identical ----------------
  for (int s = 0; s < OUTLEN; ++s) {
    const u16* xs = (s == 0) ? (pl_x + 255ULL * 16384) : (pl_y + (size_t)((s - 1) & 1) * 16384);
    const u16* h0i = pl_h0 + (size_t)(s & 1) * 262144;
    u16* h0o = pl_h0 + (size_t)((s + 1) & 1) * 262144;
    const u16* h1i = pl_h1 + (size_t)(s & 1) * 262144;
    u16* h1o = pl_h1 + (size_t)((s + 1) & 1) * 262144;

    GArgs g0{xs, pl_dWih0, 1, h0i, pl_dWhh0, 16, dbih0, dbhh0, h0i, h0o, nullptr};
    fused_gemm32<3, 0><<<dim3(64, 4), 128, 0, stream>>>(g0);
    GArgs g1{h0o, pl_dWih1, 16, h1i, pl_dWhh1, 16, dbih1, dbhh1, h1i, h1o, nullptr};
    fused_gemm32<3, 0><<<dim3(64, 4), 128, 0, stream>>>(g1);
    GArgs gp{h1o, pl_proj, 16, nullptr, nullptr, 0, projb, nullptr, nullptr, pl_p, nullptr};
    fused_gemm32<1, 1><<<dim3(32, 4), 128, 0, stream>>>(gp);
    GArgs gy{pl_p, pl_out, 8, nullptr, nullptr, 0, outb, nullptr, nullptr,
             pl_y + (size_t)(s & 1) * 16384, outf + (size_t)s * 64};
    fused_gemm32<1, 2><<<dim3(4, 4), 128, 0, stream>>>(gy);
  }
}